// Round 1
// baseline (688.121 us; speedup 1.0000x reference)
//
#include <hip/hip_runtime.h>

// Problem constants (from reference):
constexpr int B     = 32;
constexpr int N_ST  = 8;
constexpr int N_SUB = 256;
constexpr int WIN   = 2048;

// Tile: 256 w x 16 s per block, 256 threads (4 waves).
// Every wave csi load = one contiguous 1 KB segment (64 lanes x float4).
constexpr int TW  = 256;
constexpr int TS  = 16;

typedef float f4 __attribute__((ext_vector_type(4)));

__global__ __launch_bounds__(256)
void station_agg_kernel(const float* __restrict__ schedule,  // [B, WIN, N_ST]
                        const float* __restrict__ csi,       // [B, N_ST, N_SUB, WIN]
                        float* __restrict__ out)             // [B, WIN, N_SUB]
{
    // Only LDS left: transposed schedule tile (8 KB). tile2 + 2nd barrier
    // removed: the 4x4 (s x w) patch lives in acc[] and is transposed in
    // registers; the 4 waves' 16B store-quarters of each 64B out line merge
    // in L2 (line is 64B-aligned because s0 % 16 == 0).
    __shared__ float sched_t[N_ST][TW];   // [t][w]

    const int s0 = blockIdx.x * TS;
    const int w0 = blockIdx.y * TW;
    const int b  = blockIdx.z;
    const int k  = threadIdx.x;           // 0..255
    const int wv = k >> 6;                // wave 0..3
    const int l  = k & 63;                // lane 0..63

    // Stage schedule[b, w0..w0+255, 0..7] transposed -> sched_t[t][w].
    // Thread k loads w-row k's 8 weights (two float4s, 32 B aligned).
    {
        const float* sp = schedule + ((size_t)b * WIN + w0 + k) * N_ST;
        const f4 a = *(const f4*)sp;
        const f4 c = *(const f4*)(sp + 4);
        sched_t[0][k] = a.x; sched_t[1][k] = a.y;
        sched_t[2][k] = a.z; sched_t[3][k] = a.w;
        sched_t[4][k] = c.x; sched_t[5][k] = c.y;
        sched_t[6][k] = c.z; sched_t[7][k] = c.w;
    }
    __syncthreads();

    // Wave wv owns s rows srow..srow+3; lane l owns w = wl..wl+3.
    f4 acc[4];
#pragma unroll
    for (int j = 0; j < 4; ++j) acc[j] = (f4)(0.0f);

    const size_t bbase = (size_t)b * N_ST * N_SUB * WIN;
    const int    srow  = s0 + 4 * wv;
    const int    wl    = w0 + 4 * l;

    // Two half-passes over t. Each half issues ALL 16 csi loads (16 KB/wave
    // in flight, back-to-back global_load_dwordx4) before any FMA, instead
    // of the per-t load->wait->fma chain that capped MLP in v1.
#pragma unroll
    for (int h = 0; h < 2; ++h) {
        f4 cbuf[4][4];
        f4 sv[4];
#pragma unroll
        for (int tt = 0; tt < 4; ++tt) {
            const int t = 4 * h + tt;
            const float* cp = csi + bbase
                            + ((size_t)t * N_SUB + srow) * WIN + wl;
#pragma unroll
            for (int j = 0; j < 4; ++j) {
                // csi is read-once (537 MB) -> nontemporal, don't pollute L2.
                cbuf[tt][j] = __builtin_nontemporal_load((const f4*)(cp + (size_t)j * WIN));
            }
        }
#pragma unroll
        for (int tt = 0; tt < 4; ++tt) {
            // b128 LDS read, lanes 16B-contiguous -> 2-way aliasing (free).
            sv[tt] = *(const f4*)&sched_t[4 * h + tt][4 * l];
        }
#pragma unroll
        for (int tt = 0; tt < 4; ++tt) {
#pragma unroll
            for (int j = 0; j < 4; ++j) {
                acc[j] += cbuf[tt][j] * sv[tt];
            }
        }
    }

    // In-register 4x4 transpose + direct f4 stores along s.
    // acc[j][c] = out value at (s = srow+j, w = wl+c).
    // Temporal stores so L2 merges the four wave-quarters per 64B line.
    float* op = out + ((size_t)b * WIN + wl) * N_SUB + srow;
#pragma unroll
    for (int c = 0; c < 4; ++c) {
        f4 o;
        o.x = acc[0][c];
        o.y = acc[1][c];
        o.z = acc[2][c];
        o.w = acc[3][c];
        *(f4*)(op + (size_t)c * N_SUB) = o;
    }
}

extern "C" void kernel_launch(void* const* d_in, const int* in_sizes, int n_in,
                              void* d_out, int out_size, void* d_ws, size_t ws_size,
                              hipStream_t stream) {
    const float* schedule = (const float*)d_in[0];  // [B, WIN, N_ST]
    const float* csi      = (const float*)d_in[1];  // [B, N_ST, N_SUB, WIN]
    float* out            = (float*)d_out;          // [B, WIN, N_SUB]

    dim3 grid(N_SUB / TS, WIN / TW, B);   // 16 x 8 x 32 = 4096 blocks
    dim3 block(256);
    station_agg_kernel<<<grid, block, 0, stream>>>(schedule, csi, out);
}